// Round 1
// baseline (40.731 us; speedup 1.0000x reference)
//
#include <hip/hip_runtime.h>
#include <hip/hip_bf16.h>
#include <cstddef>

#define N_QUBITS 4
#define D_IN 512
#define BLOCK 256

// ---------------------------------------------------------------------------
// Kernel 1: precompute the 8 fixed Rot(phi,theta,omega) 2x2 complex matrices
// (batch-invariant). Layout in ws: gate g = l*4+q, 8 floats:
// [u00r,u00i, u01r,u01i, u10r,u10i, u11r,u11i]
// Rot = [[e^{-i(phi+om)/2} c, -e^{+i(phi-om)/2} s],
//        [e^{-i(phi-om)/2} s,  e^{+i(phi+om)/2} c]]
// ---------------------------------------------------------------------------
__global__ void qhead_pre(const float* __restrict__ w, float* __restrict__ rot)
{
    int g = threadIdx.x;
    if (g < 8) {
        float phi = w[g * 3 + 0];
        float th  = w[g * 3 + 1];
        float om  = w[g * 3 + 2];
        float sn, cs;  sincosf(th * 0.5f, &sn, &cs);
        float sa, ca;  sincosf((phi + om) * 0.5f, &sa, &ca);
        float sd, cd;  sincosf((phi - om) * 0.5f, &sd, &cd);
        float* u = rot + g * 8;
        u[0] =  cs * ca;  u[1] = -cs * sa;   // u00 = e^{-ia} c
        u[2] = -sn * cd;  u[3] = -sn * sd;   // u01 = -e^{+id} s
        u[4] =  sn * cd;  u[5] = -sn * sd;   // u10 = e^{-id} s
        u[6] =  cs * ca;  u[7] =  cs * sa;   // u11 = e^{+ia} c
    }
}

// ---------------------------------------------------------------------------
// State-vector helpers. BIT/CB/TB are template params so every state[] index
// is compile-time constant after unrolling (keeps the 16-complex state in
// VGPRs; runtime-indexed arrays would spill to scratch).
// Wire q (PennyLane: wire 0 most significant) lives at bit (3-q) of the flat
// index.
// ---------------------------------------------------------------------------
template<int BIT>
__device__ __forceinline__ void applyG(float* sr, float* si,
    float u00r, float u00i, float u01r, float u01i,
    float u10r, float u10i, float u11r, float u11i)
{
#pragma unroll
    for (int m = 0; m < 8; ++m) {
        const int lo = m & (BIT - 1);
        const int i0 = ((m ^ lo) << 1) | lo;   // insert 0 at BIT position
        const int i1 = i0 | BIT;
        float a0r = sr[i0], a0i = si[i0];
        float a1r = sr[i1], a1i = si[i1];
        float n0r = u00r * a0r - u00i * a0i + u01r * a1r - u01i * a1i;
        float n0i = u00r * a0i + u00i * a0r + u01r * a1i + u01i * a1r;
        float n1r = u10r * a0r - u10i * a0i + u11r * a1r - u11i * a1i;
        float n1i = u10r * a0i + u10i * a0r + u11r * a1i + u11i * a1r;
        sr[i0] = n0r; si[i0] = n0i;
        sr[i1] = n1r; si[i1] = n1i;
    }
}

template<int CB, int TB>   // control bit, target bit (flat-index bit masks)
__device__ __forceinline__ void applyCNOT(float* sr, float* si)
{
    constexpr int FREE = 15 & ~CB & ~TB;
    constexpr int LO = FREE & (-FREE);
    constexpr int HI = FREE ^ LO;
#pragma unroll
    for (int m = 0; m < 4; ++m) {
        const int idx = CB | ((m & 1) ? LO : 0) | ((m & 2) ? HI : 0);
        const int j = idx | TB;
        float tr = sr[idx]; sr[idx] = sr[j]; sr[j] = tr;
        float ti = si[idx]; si[idx] = si[j]; si[j] = ti;
    }
}

// ---------------------------------------------------------------------------
// Kernel 2: one batch row per thread.
//   angles = tanh(x_row . fc_w^T + b)   (float4 loads, weights from LDS)
//   16-amplitude circuit sim in registers
//   out = sum_idx |amp|^2 * (1 - popcount(idx)/2)
// ---------------------------------------------------------------------------
__global__ __launch_bounds__(BLOCK) void qhead_main(
    const float* __restrict__ x,
    const float* __restrict__ fc_w,
    const float* __restrict__ fc_b,
    const float* __restrict__ rot,
    float* __restrict__ out, int B)
{
    __shared__ float4 lw[4 * 128];   // fc_w, row j chunk k at [j*128+k]
    __shared__ float  lrot[64];

    const int t = threadIdx.x;
    const float4* w4 = (const float4*)fc_w;
#pragma unroll
    for (int i = t; i < 512; i += BLOCK) lw[i] = w4[i];
    if (t < 64) lrot[t] = rot[t];
    __syncthreads();

    const int r = blockIdx.x * BLOCK + t;
    if (r >= B) return;

    // ---- GEMM row: 4 dot products over 512 elements ----
    const float4* xr = (const float4*)(x + (size_t)r * D_IN);
    float s0 = 0.f, s1 = 0.f, s2 = 0.f, s3 = 0.f;
#pragma unroll 8
    for (int k = 0; k < 128; ++k) {
        float4 xv = xr[k];
        float4 w0 = lw[k];
        float4 w1 = lw[128 + k];
        float4 w2 = lw[256 + k];
        float4 w3 = lw[384 + k];
        s0 += xv.x * w0.x + xv.y * w0.y + xv.z * w0.z + xv.w * w0.w;
        s1 += xv.x * w1.x + xv.y * w1.y + xv.z * w1.z + xv.w * w1.w;
        s2 += xv.x * w2.x + xv.y * w2.y + xv.z * w2.z + xv.w * w2.w;
        s3 += xv.x * w3.x + xv.y * w3.y + xv.z * w3.z + xv.w * w3.w;
    }
    const float ang0 = tanhf(s0 + fc_b[0]);
    const float ang1 = tanhf(s1 + fc_b[1]);
    const float ang2 = tanhf(s2 + fc_b[2]);
    const float ang3 = tanhf(s3 + fc_b[3]);

    // ---- circuit sim: state = 16 complex amplitudes in registers ----
    float sr[16], si[16];
#pragma unroll
    for (int i = 0; i < 16; ++i) { sr[i] = 0.f; si[i] = 0.f; }
    sr[0] = 1.f;

    // AngleEmbedding: RX(ang_q) on wire q. RX = [[c,-is],[-is,c]], c/s of a/2
    {
        float hs, hc;
        sincosf(ang0 * 0.5f, &hs, &hc);
        applyG<8>(sr, si, hc, 0.f, 0.f, -hs, 0.f, -hs, hc, 0.f);
        sincosf(ang1 * 0.5f, &hs, &hc);
        applyG<4>(sr, si, hc, 0.f, 0.f, -hs, 0.f, -hs, hc, 0.f);
        sincosf(ang2 * 0.5f, &hs, &hc);
        applyG<2>(sr, si, hc, 0.f, 0.f, -hs, 0.f, -hs, hc, 0.f);
        sincosf(ang3 * 0.5f, &hs, &hc);
        applyG<1>(sr, si, hc, 0.f, 0.f, -hs, 0.f, -hs, hc, 0.f);
    }

#define ROTG(l, q)                                                         \
    {                                                                      \
        const float* u = &lrot[((l) * 4 + (q)) * 8];                       \
        applyG<(1 << (3 - (q)))>(sr, si, u[0], u[1], u[2], u[3],           \
                                 u[4], u[5], u[6], u[7]);                  \
    }

    // Layer 0: Rot on each wire, then CNOT ring range 1 (in order)
    ROTG(0, 0); ROTG(0, 1); ROTG(0, 2); ROTG(0, 3);
    applyCNOT<8, 4>(sr, si);   // (0,1)
    applyCNOT<4, 2>(sr, si);   // (1,2)
    applyCNOT<2, 1>(sr, si);   // (2,3)
    applyCNOT<1, 8>(sr, si);   // (3,0)

    // Layer 1: Rot, then CNOT ring range 2
    ROTG(1, 0); ROTG(1, 1); ROTG(1, 2); ROTG(1, 3);
    applyCNOT<8, 2>(sr, si);   // (0,2)
    applyCNOT<4, 1>(sr, si);   // (1,3)
    applyCNOT<2, 8>(sr, si);   // (2,0)
    applyCNOT<1, 4>(sr, si);   // (3,1)
#undef ROTG

    // ---- mean_k <Z_k> = sum_idx p[idx] * (1 - popcount(idx)/2) ----
    float res = 0.f;
#pragma unroll
    for (int i = 0; i < 16; ++i) {
        float p = sr[i] * sr[i] + si[i] * si[i];
        res += p * (1.0f - 0.5f * (float)__popc(i));
    }
    out[r] = res;
}

extern "C" void kernel_launch(void* const* d_in, const int* in_sizes, int n_in,
                              void* d_out, int out_size, void* d_ws, size_t ws_size,
                              hipStream_t stream)
{
    const float* x    = (const float*)d_in[0];
    const float* fc_w = (const float*)d_in[1];
    const float* fc_b = (const float*)d_in[2];
    const float* w    = (const float*)d_in[3];
    float* out = (float*)d_out;
    float* rot = (float*)d_ws;

    const int B = in_sizes[0] / D_IN;

    qhead_pre<<<1, 64, 0, stream>>>(w, rot);
    qhead_main<<<(B + BLOCK - 1) / BLOCK, BLOCK, 0, stream>>>(
        x, fc_w, fc_b, rot, out, B);
}

// Round 2
// 35.366 us; speedup vs baseline: 1.1517x; 1.1517x over previous
//
#include <hip/hip_runtime.h>
#include <hip/hip_bf16.h>
#include <cstddef>

#define D_IN 512
#define BLOCK 256
#define ROWS_PER_BLOCK 64

// ---------------------------------------------------------------------------
// Kernel 1: precompute the 8 fixed Rot(phi,theta,omega) 2x2 complex matrices
// (batch-invariant). Layout in ws: gate g = l*4+q, 8 floats:
// [u00r,u00i, u01r,u01i, u10r,u10i, u11r,u11i]
// ---------------------------------------------------------------------------
__global__ void qhead_pre(const float* __restrict__ w, float* __restrict__ rot)
{
    int g = threadIdx.x;
    if (g < 8) {
        float phi = w[g * 3 + 0];
        float th  = w[g * 3 + 1];
        float om  = w[g * 3 + 2];
        float sn, cs;  sincosf(th * 0.5f, &sn, &cs);
        float sa, ca;  sincosf((phi + om) * 0.5f, &sa, &ca);
        float sd, cd;  sincosf((phi - om) * 0.5f, &sd, &cd);
        float* u = rot + g * 8;
        u[0] =  cs * ca;  u[1] = -cs * sa;   // u00 = e^{-ia} c
        u[2] = -sn * cd;  u[3] = -sn * sd;   // u01 = -e^{+id} s
        u[4] =  sn * cd;  u[5] = -sn * sd;   // u10 = e^{-id} s
        u[6] =  cs * ca;  u[7] =  cs * sa;   // u11 = e^{+ia} c
    }
}

// ---------------------------------------------------------------------------
// State-vector helpers. BIT/CB/TB template params keep every state[] index
// compile-time constant (state stays in VGPRs; runtime indexing would go to
// scratch). Wire q (PennyLane: wire 0 most significant) = bit (3-q).
// ---------------------------------------------------------------------------
template<int BIT>
__device__ __forceinline__ void applyG(float* sr, float* si,
    float u00r, float u00i, float u01r, float u01i,
    float u10r, float u10i, float u11r, float u11i)
{
#pragma unroll
    for (int m = 0; m < 8; ++m) {
        const int lo = m & (BIT - 1);
        const int i0 = ((m ^ lo) << 1) | lo;   // insert 0 at BIT position
        const int i1 = i0 | BIT;
        float a0r = sr[i0], a0i = si[i0];
        float a1r = sr[i1], a1i = si[i1];
        float n0r = u00r * a0r - u00i * a0i + u01r * a1r - u01i * a1i;
        float n0i = u00r * a0i + u00i * a0r + u01r * a1i + u01i * a1r;
        float n1r = u10r * a0r - u10i * a0i + u11r * a1r - u11i * a1i;
        float n1i = u10r * a0i + u10i * a0r + u11r * a1i + u11i * a1r;
        sr[i0] = n0r; si[i0] = n0i;
        sr[i1] = n1r; si[i1] = n1i;
    }
}

template<int CB, int TB>   // control bit, target bit (flat-index bit masks)
__device__ __forceinline__ void applyCNOT(float* sr, float* si)
{
    constexpr int FREE = 15 & ~CB & ~TB;
    constexpr int LO = FREE & (-FREE);
    constexpr int HI = FREE ^ LO;
#pragma unroll
    for (int m = 0; m < 4; ++m) {
        const int idx = CB | ((m & 1) ? LO : 0) | ((m & 2) ? HI : 0);
        const int j = idx | TB;
        float tr = sr[idx]; sr[idx] = sr[j]; sr[j] = tr;
        float ti = si[idx]; si[idx] = si[j]; si[j] = ti;
    }
}

// ---------------------------------------------------------------------------
// Kernel 2: 64 rows per block (lane = row), K split across the 4 waves.
// Wave wv covers k in [wv*128, wv*128+128): weight addresses are wave-uniform
// -> s_load (SMEM path, SGPR-operand FMAs, no LDS/VMEM for weights).
// Partials -> 4KB LDS -> wave 0 reduces, tanh, runs the 16-amp sim, writes.
// ---------------------------------------------------------------------------
__global__ __launch_bounds__(BLOCK) void qhead_main(
    const float* __restrict__ x,
    const float* __restrict__ fc_w,
    const float* __restrict__ fc_b,
    const float* __restrict__ rot,
    float* __restrict__ out, int B)
{
    __shared__ float part[16][ROWS_PER_BLOCK];   // [wv*4+j][row]

    const int t    = threadIdx.x;
    const int lane = t & 63;
    const int wv   = __builtin_amdgcn_readfirstlane(t >> 6);  // provably SGPR
    const int row  = blockIdx.x * ROWS_PER_BLOCK + lane;

    if (row < B) {
        const float4* xr = (const float4*)(x + (size_t)row * D_IN) + wv * 32;
        const float4* wb = (const float4*)fc_w + wv * 32;   // wave-uniform

        float s0 = 0.f, s1 = 0.f, s2 = 0.f, s3 = 0.f;
#pragma unroll 8
        for (int k = 0; k < 32; ++k) {
            float4 xv = xr[k];
            float4 w0 = wb[k];
            float4 w1 = wb[128 + k];
            float4 w2 = wb[256 + k];
            float4 w3 = wb[384 + k];
            s0 += xv.x * w0.x + xv.y * w0.y + xv.z * w0.z + xv.w * w0.w;
            s1 += xv.x * w1.x + xv.y * w1.y + xv.z * w1.z + xv.w * w1.w;
            s2 += xv.x * w2.x + xv.y * w2.y + xv.z * w2.z + xv.w * w2.w;
            s3 += xv.x * w3.x + xv.y * w3.y + xv.z * w3.z + xv.w * w3.w;
        }
        part[wv * 4 + 0][lane] = s0;
        part[wv * 4 + 1][lane] = s1;
        part[wv * 4 + 2][lane] = s2;
        part[wv * 4 + 3][lane] = s3;
    }
    __syncthreads();
    if (t >= 64 || row >= B) return;   // waves 1..3 done (no later barriers)

    // ---- wave 0: reduce partials, angles, sim ----
    float ang[4];
#pragma unroll
    for (int j = 0; j < 4; ++j) {
        float s = part[j][lane] + part[4 + j][lane]
                + part[8 + j][lane] + part[12 + j][lane];
        ang[j] = tanhf(s + fc_b[j]);
    }

    float sr[16], si[16];
#pragma unroll
    for (int i = 0; i < 16; ++i) { sr[i] = 0.f; si[i] = 0.f; }
    sr[0] = 1.f;

    // AngleEmbedding: RX(ang_q) on wire q. RX = [[c,-is],[-is,c]], c/s of a/2
    {
        float hs, hc;
        sincosf(ang[0] * 0.5f, &hs, &hc);
        applyG<8>(sr, si, hc, 0.f, 0.f, -hs, 0.f, -hs, hc, 0.f);
        sincosf(ang[1] * 0.5f, &hs, &hc);
        applyG<4>(sr, si, hc, 0.f, 0.f, -hs, 0.f, -hs, hc, 0.f);
        sincosf(ang[2] * 0.5f, &hs, &hc);
        applyG<2>(sr, si, hc, 0.f, 0.f, -hs, 0.f, -hs, hc, 0.f);
        sincosf(ang[3] * 0.5f, &hs, &hc);
        applyG<1>(sr, si, hc, 0.f, 0.f, -hs, 0.f, -hs, hc, 0.f);
    }

    // Rot gate matrices: wave-uniform global reads (scalarized, L1-hot)
#define ROTG(l, q)                                                         \
    {                                                                      \
        const float* u = rot + ((l) * 4 + (q)) * 8;                        \
        applyG<(1 << (3 - (q)))>(sr, si, u[0], u[1], u[2], u[3],           \
                                 u[4], u[5], u[6], u[7]);                  \
    }

    // Layer 0: Rot on each wire, then CNOT ring range 1
    ROTG(0, 0); ROTG(0, 1); ROTG(0, 2); ROTG(0, 3);
    applyCNOT<8, 4>(sr, si);   // (0,1)
    applyCNOT<4, 2>(sr, si);   // (1,2)
    applyCNOT<2, 1>(sr, si);   // (2,3)
    applyCNOT<1, 8>(sr, si);   // (3,0)

    // Layer 1: Rot, then CNOT ring range 2
    ROTG(1, 0); ROTG(1, 1); ROTG(1, 2); ROTG(1, 3);
    applyCNOT<8, 2>(sr, si);   // (0,2)
    applyCNOT<4, 1>(sr, si);   // (1,3)
    applyCNOT<2, 8>(sr, si);   // (2,0)
    applyCNOT<1, 4>(sr, si);   // (3,1)
#undef ROTG

    // ---- mean_k <Z_k> = sum_idx p[idx] * (1 - popcount(idx)/2) ----
    float res = 0.f;
#pragma unroll
    for (int i = 0; i < 16; ++i) {
        float p = sr[i] * sr[i] + si[i] * si[i];
        res += p * (1.0f - 0.5f * (float)__popc(i));
    }
    out[row] = res;
}

extern "C" void kernel_launch(void* const* d_in, const int* in_sizes, int n_in,
                              void* d_out, int out_size, void* d_ws, size_t ws_size,
                              hipStream_t stream)
{
    const float* x    = (const float*)d_in[0];
    const float* fc_w = (const float*)d_in[1];
    const float* fc_b = (const float*)d_in[2];
    const float* w    = (const float*)d_in[3];
    float* out = (float*)d_out;
    float* rot = (float*)d_ws;

    const int B = in_sizes[0] / D_IN;

    qhead_pre<<<1, 64, 0, stream>>>(w, rot);
    qhead_main<<<(B + ROWS_PER_BLOCK - 1) / ROWS_PER_BLOCK, BLOCK, 0, stream>>>(
        x, fc_w, fc_b, rot, out, B);
}

// Round 3
// 34.082 us; speedup vs baseline: 1.1951x; 1.0377x over previous
//
#include <hip/hip_runtime.h>
#include <hip/hip_bf16.h>
#include <cstddef>

#define D_IN 512
#define ROWS_PER_WAVE 8            // 4 passes x 2 rows
#define ROWS_PER_BLOCK 32          // 4 waves

// ---------------------------------------------------------------------------
// Kernel A: angles-GEMM. K in lanes (32 lanes per row, 2 rows per wave) so
// every x load is two contiguous 512B segments (coalesced). Weights live in
// 16 float4 registers per lane (loaded once). Butterfly shfl_xor reduce over
// the 32-lane group; lanes sub<4 write the 4 raw dots per row (32B/wave
// contiguous). No LDS, no barriers.
// ---------------------------------------------------------------------------
__global__ __launch_bounds__(256) void qhead_gemm(
    const float* __restrict__ x,
    const float* __restrict__ fc_w,
    float* __restrict__ dots, int B)
{
    const int t    = threadIdx.x;
    const int lane = t & 63;
    const int wv   = t >> 6;
    const int sub  = lane & 31;    // k-slot within the row
    const int half = lane >> 5;    // which row of the pair

    // wreg[j][it] = fc_w row j, float4 chunk (it*32 + sub)
    const float4* w4 = (const float4*)fc_w;
    float4 wreg[4][4];
#pragma unroll
    for (int j = 0; j < 4; ++j)
#pragma unroll
        for (int it = 0; it < 4; ++it)
            wreg[j][it] = w4[j * 128 + it * 32 + sub];

    const int row0 = blockIdx.x * ROWS_PER_BLOCK + wv * ROWS_PER_WAVE;

#pragma unroll
    for (int p = 0; p < 4; ++p) {
        const int r = row0 + p * 2 + half;
        if (r >= B) return;
        const float4* xr = (const float4*)(x + (size_t)r * D_IN);

        float4 xv[4];
#pragma unroll
        for (int it = 0; it < 4; ++it) xv[it] = xr[it * 32 + sub];

        float s0 = 0.f, s1 = 0.f, s2 = 0.f, s3 = 0.f;
#pragma unroll
        for (int it = 0; it < 4; ++it) {
            float4 v = xv[it];
            s0 += v.x * wreg[0][it].x + v.y * wreg[0][it].y
                + v.z * wreg[0][it].z + v.w * wreg[0][it].w;
            s1 += v.x * wreg[1][it].x + v.y * wreg[1][it].y
                + v.z * wreg[1][it].z + v.w * wreg[1][it].w;
            s2 += v.x * wreg[2][it].x + v.y * wreg[2][it].y
                + v.z * wreg[2][it].z + v.w * wreg[2][it].w;
            s3 += v.x * wreg[3][it].x + v.y * wreg[3][it].y
                + v.z * wreg[3][it].z + v.w * wreg[3][it].w;
        }

        // butterfly reduce within each 32-lane group (never crosses bit 5)
#pragma unroll
        for (int off = 1; off < 32; off <<= 1) {
            s0 += __shfl_xor(s0, off);
            s1 += __shfl_xor(s1, off);
            s2 += __shfl_xor(s2, off);
            s3 += __shfl_xor(s3, off);
        }

        if (sub < 4) {
            float v = (sub == 0) ? s0 : (sub == 1) ? s1 : (sub == 2) ? s2 : s3;
            dots[(size_t)r * 4 + sub] = v;   // raw dot; bias+tanh in kernel B
        }
    }
}

// ---------------------------------------------------------------------------
// State-vector helpers. BIT/CB/TB template params keep every state[] index
// compile-time constant (state stays in VGPRs). Wire q = bit (3-q).
// ---------------------------------------------------------------------------
template<int BIT>
__device__ __forceinline__ void applyG(float* sr, float* si,
    float u00r, float u00i, float u01r, float u01i,
    float u10r, float u10i, float u11r, float u11i)
{
#pragma unroll
    for (int m = 0; m < 8; ++m) {
        const int lo = m & (BIT - 1);
        const int i0 = ((m ^ lo) << 1) | lo;
        const int i1 = i0 | BIT;
        float a0r = sr[i0], a0i = si[i0];
        float a1r = sr[i1], a1i = si[i1];
        float n0r = u00r * a0r - u00i * a0i + u01r * a1r - u01i * a1i;
        float n0i = u00r * a0i + u00i * a0r + u01r * a1i + u01i * a1r;
        float n1r = u10r * a0r - u10i * a0i + u11r * a1r - u11i * a1i;
        float n1i = u10r * a0i + u10i * a0r + u11r * a1i + u11i * a1r;
        sr[i0] = n0r; si[i0] = n0i;
        sr[i1] = n1r; si[i1] = n1i;
    }
}

template<int CB, int TB>
__device__ __forceinline__ void applyCNOT(float* sr, float* si)
{
    constexpr int FREE = 15 & ~CB & ~TB;
    constexpr int LO = FREE & (-FREE);
    constexpr int HI = FREE ^ LO;
#pragma unroll
    for (int m = 0; m < 4; ++m) {
        const int idx = CB | ((m & 1) ? LO : 0) | ((m & 2) ? HI : 0);
        const int j = idx | TB;
        float tr = sr[idx]; sr[idx] = sr[j]; sr[j] = tr;
        float ti = si[idx]; si[idx] = si[j]; si[j] = ti;
    }
}

// ---------------------------------------------------------------------------
// Kernel B: row-per-thread, fully lane-packed sim.
// Reads 4 raw dots per row (coalesced float4, L2-hot), applies bias+tanh,
// recomputes the 8 batch-invariant Rot matrices per-thread (uniform scalar
// work), runs the 16-amplitude sim in registers, writes mean<Z>.
// ---------------------------------------------------------------------------
__global__ __launch_bounds__(256) void qhead_sim(
    const float* __restrict__ dots,
    const float* __restrict__ fc_b,
    const float* __restrict__ w,
    float* __restrict__ out, int B)
{
    const int r = blockIdx.x * 256 + threadIdx.x;
    if (r >= B) return;

    // rot matrices rm[g][8]: [u00r,u00i,u01r,u01i,u10r,u10i,u11r,u11i]
    float rm[8][8];
#pragma unroll
    for (int g = 0; g < 8; ++g) {
        float phi = w[g * 3 + 0];
        float th  = w[g * 3 + 1];
        float om  = w[g * 3 + 2];
        float sn, cs;  sincosf(th * 0.5f, &sn, &cs);
        float sa, ca;  sincosf((phi + om) * 0.5f, &sa, &ca);
        float sd, cd;  sincosf((phi - om) * 0.5f, &sd, &cd);
        rm[g][0] =  cs * ca;  rm[g][1] = -cs * sa;
        rm[g][2] = -sn * cd;  rm[g][3] = -sn * sd;
        rm[g][4] =  sn * cd;  rm[g][5] = -sn * sd;
        rm[g][6] =  cs * ca;  rm[g][7] =  cs * sa;
    }

    float4 d = ((const float4*)dots)[r];
    const float ang0 = tanhf(d.x + fc_b[0]);
    const float ang1 = tanhf(d.y + fc_b[1]);
    const float ang2 = tanhf(d.z + fc_b[2]);
    const float ang3 = tanhf(d.w + fc_b[3]);

    float sr[16], si[16];
#pragma unroll
    for (int i = 0; i < 16; ++i) { sr[i] = 0.f; si[i] = 0.f; }
    sr[0] = 1.f;

    // AngleEmbedding: RX = [[c,-is],[-is,c]], c/s of angle/2
    {
        float hs, hc;
        sincosf(ang0 * 0.5f, &hs, &hc);
        applyG<8>(sr, si, hc, 0.f, 0.f, -hs, 0.f, -hs, hc, 0.f);
        sincosf(ang1 * 0.5f, &hs, &hc);
        applyG<4>(sr, si, hc, 0.f, 0.f, -hs, 0.f, -hs, hc, 0.f);
        sincosf(ang2 * 0.5f, &hs, &hc);
        applyG<2>(sr, si, hc, 0.f, 0.f, -hs, 0.f, -hs, hc, 0.f);
        sincosf(ang3 * 0.5f, &hs, &hc);
        applyG<1>(sr, si, hc, 0.f, 0.f, -hs, 0.f, -hs, hc, 0.f);
    }

#define ROTG(l, q)                                                          \
    applyG<(1 << (3 - (q)))>(sr, si,                                        \
        rm[(l) * 4 + (q)][0], rm[(l) * 4 + (q)][1], rm[(l) * 4 + (q)][2],   \
        rm[(l) * 4 + (q)][3], rm[(l) * 4 + (q)][4], rm[(l) * 4 + (q)][5],   \
        rm[(l) * 4 + (q)][6], rm[(l) * 4 + (q)][7]);

    // Layer 0: Rot on each wire, then CNOT ring range 1
    ROTG(0, 0); ROTG(0, 1); ROTG(0, 2); ROTG(0, 3);
    applyCNOT<8, 4>(sr, si);   // (0,1)
    applyCNOT<4, 2>(sr, si);   // (1,2)
    applyCNOT<2, 1>(sr, si);   // (2,3)
    applyCNOT<1, 8>(sr, si);   // (3,0)

    // Layer 1: Rot, then CNOT ring range 2
    ROTG(1, 0); ROTG(1, 1); ROTG(1, 2); ROTG(1, 3);
    applyCNOT<8, 2>(sr, si);   // (0,2)
    applyCNOT<4, 1>(sr, si);   // (1,3)
    applyCNOT<2, 8>(sr, si);   // (2,0)
    applyCNOT<1, 4>(sr, si);   // (3,1)
#undef ROTG

    float res = 0.f;
#pragma unroll
    for (int i = 0; i < 16; ++i) {
        float p = sr[i] * sr[i] + si[i] * si[i];
        res += p * (1.0f - 0.5f * (float)__popc(i));
    }
    out[r] = res;
}

extern "C" void kernel_launch(void* const* d_in, const int* in_sizes, int n_in,
                              void* d_out, int out_size, void* d_ws, size_t ws_size,
                              hipStream_t stream)
{
    const float* x    = (const float*)d_in[0];
    const float* fc_w = (const float*)d_in[1];
    const float* fc_b = (const float*)d_in[2];
    const float* w    = (const float*)d_in[3];
    float* out  = (float*)d_out;
    float* dots = (float*)d_ws;          // 65536*4 floats = 1 MB scratch

    const int B = in_sizes[0] / D_IN;

    qhead_gemm<<<(B + ROWS_PER_BLOCK - 1) / ROWS_PER_BLOCK, 256, 0, stream>>>(
        x, fc_w, dots, B);
    qhead_sim<<<(B + 255) / 256, 256, 0, stream>>>(dots, fc_b, w, out, B);
}